// Round 3
// baseline (193.169 us; speedup 1.0000x reference)
//
#include <hip/hip_runtime.h>

// GCN aggregation: out = A @ embeds, A in COO with SORTED rows.
// N=100000, E=1.6M, D=64.
//
// Structure: memset(out) + prep (quantize + row_ptr, grid-partitioned)
// then q8 gather. int8 table w/ per-row scale (6.4 MB, 64 B/row) passes
// absmax (0.094 vs 0.296).
//
// R1 lesson: issue-count reduction was NULL -> latency-bound.
// R2 lesson: row-pair interleave REGRESSED (44.5us gather, occ 33%,
//   VALUBusy 29%): halved wave count + degenerate serial drains. Wave
//   count + balance dominate per-group MLP.
// R3: edge-parallel BALANCED chunks. 16 lanes x 32-edge chunk per group
//   (4 dims/lane), 800k threads (12 waves/SIMD nominal). Every group does
//   exactly 32 edges. Row flush on change: interior rows (row_ptr fully
//   inside chunk, ~53%) plain store; boundary rows atomicAdd into
//   zero-initialized out. Zero-degree rows correct via memset.

#define GCN_D 64

typedef float f4 __attribute__((ext_vector_type(4)));
typedef int   i4 __attribute__((ext_vector_type(4)));

__global__ __launch_bounds__(256) void prep_kernel(
    const float* __restrict__ embeds,
    unsigned char* __restrict__ ebq,    // N x 64 uint8 (offset-128)
    float* __restrict__ scale,          // N fp32 per-row scales
    int quant_blocks,
    const int* __restrict__ edge_row, int* __restrict__ row_ptr, int E, int N)
{
    if ((int)blockIdx.x < quant_blocks) {
        // 8 lanes per row, 8 dims (32 B) per lane.
        const int t   = blockIdx.x * blockDim.x + threadIdx.x;
        const int row = t >> 3;
        if (row >= N) return;
        const int l8 = (threadIdx.x & 7) * 8;

        const f4 a = __builtin_nontemporal_load(
            (const f4*)(embeds + (size_t)row * GCN_D + l8));
        const f4 b = __builtin_nontemporal_load(
            (const f4*)(embeds + (size_t)row * GCN_D + l8 + 4));

        float m = fmaxf(fmaxf(fmaxf(fabsf(a.x), fabsf(a.y)),
                              fmaxf(fabsf(a.z), fabsf(a.w))),
                        fmaxf(fmaxf(fabsf(b.x), fabsf(b.y)),
                              fmaxf(fabsf(b.z), fabsf(b.w))));
        m = fmaxf(m, __shfl_xor(m, 1));
        m = fmaxf(m, __shfl_xor(m, 2));
        m = fmaxf(m, __shfl_xor(m, 4));

        const float inv = (m > 0.f) ? 127.f / m : 0.f;
        const int q0 = (int)rintf(fminf(fmaxf(a.x * inv, -127.f), 127.f)) + 128;
        const int q1 = (int)rintf(fminf(fmaxf(a.y * inv, -127.f), 127.f)) + 128;
        const int q2 = (int)rintf(fminf(fmaxf(a.z * inv, -127.f), 127.f)) + 128;
        const int q3 = (int)rintf(fminf(fmaxf(a.w * inv, -127.f), 127.f)) + 128;
        const int q4 = (int)rintf(fminf(fmaxf(b.x * inv, -127.f), 127.f)) + 128;
        const int q5 = (int)rintf(fminf(fmaxf(b.y * inv, -127.f), 127.f)) + 128;
        const int q6 = (int)rintf(fminf(fmaxf(b.z * inv, -127.f), 127.f)) + 128;
        const int q7 = (int)rintf(fminf(fmaxf(b.w * inv, -127.f), 127.f)) + 128;

        unsigned int p0 =
            (unsigned)q0 | ((unsigned)q1 << 8) | ((unsigned)q2 << 16) | ((unsigned)q3 << 24);
        unsigned int p1 =
            (unsigned)q4 | ((unsigned)q5 << 8) | ((unsigned)q6 << 16) | ((unsigned)q7 << 24);

        unsigned int* dst = (unsigned int*)(ebq + (size_t)row * GCN_D + l8);
        dst[0] = p0;
        dst[1] = p1;
        if ((threadIdx.x & 7) == 0) scale[row] = m * (1.f / 127.f);
    } else {
        const int e = (blockIdx.x - quant_blocks) * blockDim.x + threadIdx.x;
        if (e >= E) return;
        const int r    = edge_row[e];
        const int prev = (e == 0) ? -1 : edge_row[e - 1];
        for (int k = prev + 1; k <= r; ++k) row_ptr[k] = e;
        if (e == E - 1)
            for (int k = r + 1; k <= N; ++k) row_ptr[k] = E;
    }
}

__device__ __forceinline__ void q8_fma4(unsigned int g, float w, f4& acc) {
    acc.x += w * (float)( g        & 0xffu);
    acc.y += w * (float)((g >> 8)  & 0xffu);
    acc.z += w * (float)((g >> 16) & 0xffu);
    acc.w += w * (float)( g >> 24);
}

#define CHUNK 32

__global__ __launch_bounds__(256) void gcn_edge_q8_kernel(
    const int* __restrict__ edge_row,
    const int* __restrict__ row_ptr,
    const int* __restrict__ edge_col,
    const float* __restrict__ edge_val,
    const unsigned char* __restrict__ ebq,
    const float* __restrict__ scale,
    float* __restrict__ out,
    int E)
{
    const int tid = blockIdx.x * blockDim.x + threadIdx.x;
    const int grp = tid >> 4;
    const int k0  = grp * CHUNK;
    if (k0 >= E) return;
    const int k1 = min(k0 + CHUNK, E);
    const int db = (threadIdx.x & 15) * 4;  // byte off in table row == float off in out row

    int   r   = edge_row[k0];
    f4    acc = (f4)0.0f;
    float ws  = 0.0f;

    auto flush = [&](int rr, f4 a, float w) {
        a = a - 128.0f * w;                 // fold out offset-128 zero point
        float* dst = out + (size_t)rr * GCN_D + db;
        const bool interior = (row_ptr[rr] >= k0) && (row_ptr[rr + 1] <= k1);
        if (interior) {
            __builtin_nontemporal_store(a, (f4*)dst);
        } else {
            atomicAdd(dst + 0, a.x);
            atomicAdd(dst + 1, a.y);
            atomicAdd(dst + 2, a.z);
            atomicAdd(dst + 3, a.w);
        }
    };

    int k = k0;
    if (k + 3 < k1) {
        // double-buffered 4-edge batches; chunk edges are contiguous & 16B-aligned
        i4 rrA, cA; f4 vA; unsigned gA0, gA1, gA2, gA3; float sA0, sA1, sA2, sA3;
        rrA = *(const i4*)(edge_row + k);
        cA  = *(const i4*)(edge_col + k);
        vA  = *(const f4*)(edge_val + k);
        gA0 = *(const unsigned*)(ebq + (size_t)cA.x * GCN_D + db); sA0 = scale[cA.x];
        gA1 = *(const unsigned*)(ebq + (size_t)cA.y * GCN_D + db); sA1 = scale[cA.y];
        gA2 = *(const unsigned*)(ebq + (size_t)cA.z * GCN_D + db); sA2 = scale[cA.z];
        gA3 = *(const unsigned*)(ebq + (size_t)cA.w * GCN_D + db); sA3 = scale[cA.w];

        for (; k + 3 < k1; k += 4) {
            i4 rrB, cB; f4 vB; unsigned gB0, gB1, gB2, gB3; float sB0, sB1, sB2, sB3;
            const bool more = (k + 7 < k1);
            if (more) {
                rrB = *(const i4*)(edge_row + k + 4);
                cB  = *(const i4*)(edge_col + k + 4);
                vB  = *(const f4*)(edge_val + k + 4);
                gB0 = *(const unsigned*)(ebq + (size_t)cB.x * GCN_D + db); sB0 = scale[cB.x];
                gB1 = *(const unsigned*)(ebq + (size_t)cB.y * GCN_D + db); sB1 = scale[cB.y];
                gB2 = *(const unsigned*)(ebq + (size_t)cB.z * GCN_D + db); sB2 = scale[cB.z];
                gB3 = *(const unsigned*)(ebq + (size_t)cB.w * GCN_D + db); sB3 = scale[cB.w];
            }

            // process current batch serially (row-change check is group-uniform)
            if (rrA.x != r) { flush(r, acc, ws); acc = (f4)0.0f; ws = 0.0f; r = rrA.x; }
            { const float w = vA.x * sA0; q8_fma4(gA0, w, acc); ws += w; }
            if (rrA.y != r) { flush(r, acc, ws); acc = (f4)0.0f; ws = 0.0f; r = rrA.y; }
            { const float w = vA.y * sA1; q8_fma4(gA1, w, acc); ws += w; }
            if (rrA.z != r) { flush(r, acc, ws); acc = (f4)0.0f; ws = 0.0f; r = rrA.z; }
            { const float w = vA.z * sA2; q8_fma4(gA2, w, acc); ws += w; }
            if (rrA.w != r) { flush(r, acc, ws); acc = (f4)0.0f; ws = 0.0f; r = rrA.w; }
            { const float w = vA.w * sA3; q8_fma4(gA3, w, acc); ws += w; }

            if (more) {
                rrA = rrB; cA = cB; vA = vB;
                gA0 = gB0; gA1 = gB1; gA2 = gB2; gA3 = gB3;
                sA0 = sB0; sA1 = sB1; sA2 = sB2; sA3 = sB3;
            }
        }
    }
    for (; k < k1; ++k) {                    // scalar tail (last chunk only)
        const int rj = edge_row[k];
        if (rj != r) { flush(r, acc, ws); acc = (f4)0.0f; ws = 0.0f; r = rj; }
        const int c = edge_col[k];
        const unsigned g = *(const unsigned*)(ebq + (size_t)c * GCN_D + db);
        const float w = edge_val[k] * scale[c];
        q8_fma4(g, w, acc);
        ws += w;
    }
    flush(r, acc, ws);
}

extern "C" void kernel_launch(void* const* d_in, const int* in_sizes, int n_in,
                              void* d_out, int out_size, void* d_ws, size_t ws_size,
                              hipStream_t stream) {
    const int*   edge_row = (const int*)d_in[0];
    const int*   edge_col = (const int*)d_in[1];
    const float* edge_val = (const float*)d_in[2];
    const float* embeds   = (const float*)d_in[3];
    float*       out      = (float*)d_out;

    const int E = in_sizes[0];
    const int N = out_size / GCN_D;          // out_size is float count

    // ws layout: row_ptr | scale | int8 table (256B-aligned sections)
    int* row_ptr = (int*)d_ws;
    const size_t sc_off = (((size_t)(N + 1) * 4) + 255) & ~(size_t)255;
    float* scale = (float*)((char*)d_ws + sc_off);
    const size_t q_off = ((sc_off + (size_t)N * 4) + 255) & ~(size_t)255;
    unsigned char* ebq = (unsigned char*)d_ws + q_off;

    // zero output first: boundary rows accumulate via atomicAdd, and
    // zero-degree rows must read back 0.
    hipMemsetAsync(d_out, 0, (size_t)out_size * sizeof(float), stream);

    const int quant_blocks = (N * 8 + 255) / 256;   // 8 lanes per row
    const int rp_blocks    = (E + 255) / 256;
    prep_kernel<<<quant_blocks + rp_blocks, 256, 0, stream>>>(
        embeds, ebq, scale, quant_blocks, edge_row, row_ptr, E, N);

    const int groups       = (E + CHUNK - 1) / CHUNK;       // 50k groups
    const int gather_blocks = (groups * 16 + 255) / 256;    // 16 lanes/group
    gcn_edge_q8_kernel<<<gather_blocks, 256, 0, stream>>>(
        edge_row, row_ptr, edge_col, edge_val, ebq, scale, out, E);
}

// Round 4
// 156.376 us; speedup vs baseline: 1.2353x; 1.2353x over previous
//
#include <hip/hip_runtime.h>

// GCN aggregation: out = A @ embeds, A in COO with SORTED rows.
// N=100000, E=1.6M, D=64.
//
// Structure: prep (quantize + row_ptr, grid-partitioned) then q8 gather.
// int8 table w/ per-row scale (6.4 MB, 64 B/row) passes absmax
// (0.094 vs 0.296).
//
// R1 lesson: issue-count reduction NULL -> latency-bound.
// R2 lesson: row-pair interleave REGRESSED (fewer waves, serial drains).
// R3 lesson: edge-parallel + atomicAdd REGRESSED 2x (WRITE 26->107 MB,
//   atomics serialize). Occupancy was never the constraint.
// R4: ONE WAVE PER ROW, one dim per lane. row/p0/p1/k/col/val/scale are
//   wave-uniform (readfirstlane-forced) -> scalar-pipe s_loads; the ONLY
//   VMEM inst per edge is a 64-lane ubyte gather of one contiguous 64 B
//   table line. 100k waves queue ~97/SIMD: runtime ~ sum(deg), no
//   max(deg) imbalance tax. No atomics, no memset (zero-degree rows
//   store 0 from their own wave).

#define GCN_D 64

typedef float f4 __attribute__((ext_vector_type(4)));

__global__ __launch_bounds__(256) void prep_kernel(
    const float* __restrict__ embeds,
    unsigned char* __restrict__ ebq,    // N x 64 uint8 (offset-128)
    float* __restrict__ scale,          // N fp32 per-row scales
    int quant_blocks,
    const int* __restrict__ edge_row, int* __restrict__ row_ptr, int E, int N)
{
    if ((int)blockIdx.x < quant_blocks) {
        // 8 lanes per row, 8 dims (32 B) per lane.
        const int t   = blockIdx.x * blockDim.x + threadIdx.x;
        const int row = t >> 3;
        if (row >= N) return;
        const int l8 = (threadIdx.x & 7) * 8;

        const f4 a = __builtin_nontemporal_load(
            (const f4*)(embeds + (size_t)row * GCN_D + l8));
        const f4 b = __builtin_nontemporal_load(
            (const f4*)(embeds + (size_t)row * GCN_D + l8 + 4));

        float m = fmaxf(fmaxf(fmaxf(fabsf(a.x), fabsf(a.y)),
                              fmaxf(fabsf(a.z), fabsf(a.w))),
                        fmaxf(fmaxf(fabsf(b.x), fabsf(b.y)),
                              fmaxf(fabsf(b.z), fabsf(b.w))));
        m = fmaxf(m, __shfl_xor(m, 1));
        m = fmaxf(m, __shfl_xor(m, 2));
        m = fmaxf(m, __shfl_xor(m, 4));

        const float inv = (m > 0.f) ? 127.f / m : 0.f;
        const int q0 = (int)rintf(fminf(fmaxf(a.x * inv, -127.f), 127.f)) + 128;
        const int q1 = (int)rintf(fminf(fmaxf(a.y * inv, -127.f), 127.f)) + 128;
        const int q2 = (int)rintf(fminf(fmaxf(a.z * inv, -127.f), 127.f)) + 128;
        const int q3 = (int)rintf(fminf(fmaxf(a.w * inv, -127.f), 127.f)) + 128;
        const int q4 = (int)rintf(fminf(fmaxf(b.x * inv, -127.f), 127.f)) + 128;
        const int q5 = (int)rintf(fminf(fmaxf(b.y * inv, -127.f), 127.f)) + 128;
        const int q6 = (int)rintf(fminf(fmaxf(b.z * inv, -127.f), 127.f)) + 128;
        const int q7 = (int)rintf(fminf(fmaxf(b.w * inv, -127.f), 127.f)) + 128;

        unsigned int p0 =
            (unsigned)q0 | ((unsigned)q1 << 8) | ((unsigned)q2 << 16) | ((unsigned)q3 << 24);
        unsigned int p1 =
            (unsigned)q4 | ((unsigned)q5 << 8) | ((unsigned)q6 << 16) | ((unsigned)q7 << 24);

        unsigned int* dst = (unsigned int*)(ebq + (size_t)row * GCN_D + l8);
        dst[0] = p0;
        dst[1] = p1;
        if ((threadIdx.x & 7) == 0) scale[row] = m * (1.f / 127.f);
    } else {
        const int e = (blockIdx.x - quant_blocks) * blockDim.x + threadIdx.x;
        if (e >= E) return;
        const int r    = edge_row[e];
        const int prev = (e == 0) ? -1 : edge_row[e - 1];
        for (int k = prev + 1; k <= r; ++k) row_ptr[k] = e;
        if (e == E - 1)
            for (int k = r + 1; k <= N; ++k) row_ptr[k] = E;
    }
}

__global__ __launch_bounds__(256) void gcn_wave_q8_kernel(
    const int* __restrict__ row_ptr,
    const int* __restrict__ edge_col,
    const float* __restrict__ edge_val,
    const unsigned char* __restrict__ ebq,
    const float* __restrict__ scale,
    float* __restrict__ out,
    int N)
{
    // One wave per row. Force wave-uniformity so the edge stream
    // (col/val/scale/row_ptr) compiles to scalar-pipe s_loads.
    const int row = __builtin_amdgcn_readfirstlane(
        (int)((blockIdx.x * blockDim.x + threadIdx.x) >> 6));
    if (row >= N) return;
    const int lane = (int)(threadIdx.x & 63);

    const int p0 = row_ptr[row];
    const int p1 = row_ptr[row + 1];

    float acc = 0.0f;   // this lane's dim
    float ws  = 0.0f;   // sum of weights (same in all lanes)
    int k = p0;

    for (; k + 7 < p1; k += 8) {
        int   c[8];
        float v[8];
        #pragma unroll
        for (int j = 0; j < 8; ++j) { c[j] = edge_col[k + j]; v[j] = edge_val[k + j]; }
        unsigned g[8];
        float    s[8];
        #pragma unroll
        for (int j = 0; j < 8; ++j) {
            g[j] = ebq[(size_t)c[j] * GCN_D + lane];   // 64 lanes = one 64B line
            s[j] = scale[c[j]];
        }
        #pragma unroll
        for (int j = 0; j < 8; ++j) {
            const float w = v[j] * s[j];
            acc = fmaf(w, (float)g[j], acc);
            ws += w;
        }
    }
    if (k + 3 < p1) {
        int   c[4];
        float v[4];
        #pragma unroll
        for (int j = 0; j < 4; ++j) { c[j] = edge_col[k + j]; v[j] = edge_val[k + j]; }
        unsigned g[4];
        float    s[4];
        #pragma unroll
        for (int j = 0; j < 4; ++j) {
            g[j] = ebq[(size_t)c[j] * GCN_D + lane];
            s[j] = scale[c[j]];
        }
        #pragma unroll
        for (int j = 0; j < 4; ++j) {
            const float w = v[j] * s[j];
            acc = fmaf(w, (float)g[j], acc);
            ws += w;
        }
        k += 4;
    }
    for (; k < p1; ++k) {
        const int c = edge_col[k];
        const unsigned g = ebq[(size_t)c * GCN_D + lane];
        const float w = edge_val[k] * scale[c];
        acc = fmaf(w, (float)g, acc);
        ws += w;
    }

    // fold out the offset-128 zero point; zero-degree rows store 0.
    __builtin_nontemporal_store(acc - 128.0f * ws,
                                out + (size_t)row * GCN_D + lane);
}

extern "C" void kernel_launch(void* const* d_in, const int* in_sizes, int n_in,
                              void* d_out, int out_size, void* d_ws, size_t ws_size,
                              hipStream_t stream) {
    const int*   edge_row = (const int*)d_in[0];
    const int*   edge_col = (const int*)d_in[1];
    const float* edge_val = (const float*)d_in[2];
    const float* embeds   = (const float*)d_in[3];
    float*       out      = (float*)d_out;

    const int E = in_sizes[0];
    const int N = out_size / GCN_D;

    // ws layout: row_ptr | scale | int8 table (256B-aligned sections)
    int* row_ptr = (int*)d_ws;
    const size_t sc_off = (((size_t)(N + 1) * 4) + 255) & ~(size_t)255;
    float* scale = (float*)((char*)d_ws + sc_off);
    const size_t q_off = ((sc_off + (size_t)N * 4) + 255) & ~(size_t)255;
    unsigned char* ebq = (unsigned char*)d_ws + q_off;

    const int quant_blocks = (N * 8 + 255) / 256;   // 8 lanes per row
    const int rp_blocks    = (E + 255) / 256;
    prep_kernel<<<quant_blocks + rp_blocks, 256, 0, stream>>>(
        embeds, ebq, scale, quant_blocks, edge_row, row_ptr, E, N);

    const int gather_blocks = (N * 64 + 255) / 256;  // one wave per row
    gcn_wave_q8_kernel<<<gather_blocks, 256, 0, stream>>>(
        row_ptr, edge_col, edge_val, ebq, scale, out, N);
}

// Round 5
// 139.648 us; speedup vs baseline: 1.3833x; 1.1198x over previous
//
#include <hip/hip_runtime.h>

// GCN aggregation: out = A @ embeds, A in COO with SORTED rows.
// N=100000, E=1.6M, D=64.
//
// 3-launch structure:
//   1. quant: int8 table w/ per-row scale (6.4 MB, 64 B/row; absmax 0.094
//      vs 0.296 threshold).
//   2. edge pass (edge-parallel, balanced): row_ptr build + pack
//      pw[e] = (col[e], val[e]*scale[col[e]]) as int2. Removes the
//      per-edge scale gather from the latency-critical row loop.
//   3. gather: 16 lanes/row x 4 rows/wave (best-known structure, R0),
//      8-edge batches, EXPLICIT ping-pong pipeline so batch i+1's loads
//      fly during batch i's compute; w=0 padding kills the serial tail.
//
// R1: issue-count reduction NULL. R2: row-pair interleave regressed
// (fewer waves). R3: atomics regressed 2x (WRITE 26->107 MB). R4:
// wave-per-row ubyte regressed 1.7x (4x VMEM insts) despite occ 67%.
// Remaining theory: program-order serialization of the dependent
// col->gather chain; this round overlaps it.

#define GCN_D 64

typedef float f4 __attribute__((ext_vector_type(4)));

__global__ __launch_bounds__(256) void quant_kernel(
    const float* __restrict__ embeds,
    unsigned char* __restrict__ ebq,    // N x 64 uint8 (offset-128)
    float* __restrict__ scale,          // N fp32 per-row scales
    int N)
{
    // 8 lanes per row, 8 dims (32 B) per lane.
    const int t   = blockIdx.x * blockDim.x + threadIdx.x;
    const int row = t >> 3;
    if (row >= N) return;
    const int l8 = (threadIdx.x & 7) * 8;

    const f4 a = __builtin_nontemporal_load(
        (const f4*)(embeds + (size_t)row * GCN_D + l8));
    const f4 b = __builtin_nontemporal_load(
        (const f4*)(embeds + (size_t)row * GCN_D + l8 + 4));

    float m = fmaxf(fmaxf(fmaxf(fabsf(a.x), fabsf(a.y)),
                          fmaxf(fabsf(a.z), fabsf(a.w))),
                    fmaxf(fmaxf(fabsf(b.x), fabsf(b.y)),
                          fmaxf(fabsf(b.z), fabsf(b.w))));
    m = fmaxf(m, __shfl_xor(m, 1));
    m = fmaxf(m, __shfl_xor(m, 2));
    m = fmaxf(m, __shfl_xor(m, 4));

    const float inv = (m > 0.f) ? 127.f / m : 0.f;
    const int q0 = (int)rintf(fminf(fmaxf(a.x * inv, -127.f), 127.f)) + 128;
    const int q1 = (int)rintf(fminf(fmaxf(a.y * inv, -127.f), 127.f)) + 128;
    const int q2 = (int)rintf(fminf(fmaxf(a.z * inv, -127.f), 127.f)) + 128;
    const int q3 = (int)rintf(fminf(fmaxf(a.w * inv, -127.f), 127.f)) + 128;
    const int q4 = (int)rintf(fminf(fmaxf(b.x * inv, -127.f), 127.f)) + 128;
    const int q5 = (int)rintf(fminf(fmaxf(b.y * inv, -127.f), 127.f)) + 128;
    const int q6 = (int)rintf(fminf(fmaxf(b.z * inv, -127.f), 127.f)) + 128;
    const int q7 = (int)rintf(fminf(fmaxf(b.w * inv, -127.f), 127.f)) + 128;

    unsigned int p0 =
        (unsigned)q0 | ((unsigned)q1 << 8) | ((unsigned)q2 << 16) | ((unsigned)q3 << 24);
    unsigned int p1 =
        (unsigned)q4 | ((unsigned)q5 << 8) | ((unsigned)q6 << 16) | ((unsigned)q7 << 24);

    unsigned int* dst = (unsigned int*)(ebq + (size_t)row * GCN_D + l8);
    dst[0] = p0;
    dst[1] = p1;
    if ((threadIdx.x & 7) == 0) scale[row] = m * (1.f / 127.f);
}

__global__ __launch_bounds__(256) void edge_kernel(
    const int* __restrict__ edge_row,
    const int* __restrict__ edge_col,
    const float* __restrict__ edge_val,
    const float* __restrict__ scale,
    int* __restrict__ row_ptr,
    int2* __restrict__ pw,              // packed (col, val*scale[col])
    int E, int N)
{
    const int e = blockIdx.x * blockDim.x + threadIdx.x;
    if (e >= E) return;
    const int r    = edge_row[e];
    const int prev = (e == 0) ? -1 : edge_row[e - 1];
    for (int k = prev + 1; k <= r; ++k) row_ptr[k] = e;
    if (e == E - 1)
        for (int k = r + 1; k <= N; ++k) row_ptr[k] = E;

    const int   c = edge_col[e];
    const float w = edge_val[e] * scale[c];
    pw[e] = make_int2(c, __float_as_int(w));
}

__device__ __forceinline__ void q8_fma4(unsigned int g, float w, f4& acc) {
    acc.x += w * (float)( g        & 0xffu);
    acc.y += w * (float)((g >> 8)  & 0xffu);
    acc.z += w * (float)((g >> 16) & 0xffu);
    acc.w += w * (float)( g >> 24);
}

__global__ __launch_bounds__(256) void gcn_row_q8_kernel(
    const int* __restrict__ row_ptr,
    const int2* __restrict__ pw,
    const unsigned char* __restrict__ ebq,
    float* __restrict__ out,
    int N)
{
    const int tid = blockIdx.x * blockDim.x + threadIdx.x;
    const int row = tid >> 4;
    if (row >= N) return;
    const int db = (threadIdx.x & 15) * 4;   // byte offset into 64B row

    const int p0 = row_ptr[row];
    const int p1 = row_ptr[row + 1];

    f4    acc = (f4)0.0f;
    float ws  = 0.0f;

    if (p1 > p0) {
        const int nb = (p1 - p0 + 7) >> 3;   // padded 8-edge batches
        int k = p0;

        int      cA[8], cB[8];
        float    wA[8], wB[8];
        unsigned gA[8], gB[8];

        auto LOAD = [&](int kk, int* c, float* w, unsigned* g) {
            #pragma unroll
            for (int j = 0; j < 8; ++j) {
                const int idx = (kk + j < p1) ? (kk + j) : (p1 - 1);
                const int2 t  = pw[idx];
                c[j] = t.x;
                w[j] = (kk + j < p1) ? __int_as_float(t.y) : 0.0f;
            }
            #pragma unroll
            for (int j = 0; j < 8; ++j)
                g[j] = *(const unsigned*)(ebq + (size_t)c[j] * GCN_D + db);
        };
        auto COMP = [&](const float* w, const unsigned* g) {
            #pragma unroll
            for (int j = 0; j < 8; ++j) {
                q8_fma4(g[j], w[j], acc);
                ws += w[j];
            }
        };

        // ping-pong pipeline: next batch's loads fly during this compute
        LOAD(k, cA, wA, gA); k += 8;
        int b = 1;
        for (; b + 1 < nb; b += 2) {
            LOAD(k, cB, wB, gB); k += 8;
            COMP(wA, gA);
            LOAD(k, cA, wA, gA); k += 8;
            COMP(wB, gB);
        }
        if (b < nb) {
            LOAD(k, cB, wB, gB);
            COMP(wA, gA);
            COMP(wB, gB);
        } else {
            COMP(wA, gA);
        }
    }

    acc = acc - 128.0f * ws;   // fold out the offset-128 zero point
    __builtin_nontemporal_store(acc, (f4*)(out + (size_t)row * GCN_D + db));
}

extern "C" void kernel_launch(void* const* d_in, const int* in_sizes, int n_in,
                              void* d_out, int out_size, void* d_ws, size_t ws_size,
                              hipStream_t stream) {
    const int*   edge_row = (const int*)d_in[0];
    const int*   edge_col = (const int*)d_in[1];
    const float* edge_val = (const float*)d_in[2];
    const float* embeds   = (const float*)d_in[3];
    float*       out      = (float*)d_out;

    const int E = in_sizes[0];
    const int N = out_size / GCN_D;

    // ws layout: row_ptr | scale | pw (int2 per edge) | int8 table
    int* row_ptr = (int*)d_ws;
    const size_t sc_off = (((size_t)(N + 1) * 4) + 255) & ~(size_t)255;
    float* scale = (float*)((char*)d_ws + sc_off);
    const size_t pw_off = ((sc_off + (size_t)N * 4) + 255) & ~(size_t)255;
    int2* pw = (int2*)((char*)d_ws + pw_off);
    const size_t q_off = ((pw_off + (size_t)E * 8) + 255) & ~(size_t)255;
    unsigned char* ebq = (unsigned char*)d_ws + q_off;

    const int quant_blocks = (N * 8 + 255) / 256;   // 8 lanes per row
    quant_kernel<<<quant_blocks, 256, 0, stream>>>(embeds, ebq, scale, N);

    const int edge_blocks = (E + 255) / 256;
    edge_kernel<<<edge_blocks, 256, 0, stream>>>(
        edge_row, edge_col, edge_val, scale, row_ptr, pw, E, N);

    const int row_blocks = (N * 16 + 255) / 256;    // 16 lanes per row
    gcn_row_q8_kernel<<<row_blocks, 256, 0, stream>>>(
        row_ptr, pw, ebq, out, N);
}

// Round 6
// 137.071 us; speedup vs baseline: 1.4093x; 1.0188x over previous
//
#include <hip/hip_runtime.h>

// GCN aggregation: out = A @ embeds, A in COO with SORTED rows.
// N=100000, E=1.6M, D=64.
//
// 2-launch structure (R0 skeleton):
//   1. prep (grid-partitioned): bf16-convert embeds (N x 64 bf16 table,
//      12.8 MB, L3-resident) + row_ptr build.
//   2. gather: 16 lanes/row x 4 rows/wave, 8-edge ping-pong pipeline
//      (R5's overlap, without R5's extra launch/pw traffic).
//
// Round ledger: R1 issue-count NULL; R2 row-pair regress (fewer waves);
// R3 atomics regress 2x (WRITE 26->107MB); R4 wave-per-row regress 1.7x
// (4x VMEM insts); R5 3-launch pw pipeline net -13us (launch + 25MB pw
// traffic > pipeline gain). Total ~= gather + ~91us harness constant.
//
// R6: bf16 table replaces q8+scale. Kills the per-edge scale gather
// (4->3 VMEM/edge) and the zero-point/wsum path (bf16->f32 = shift/and;
// per-edge VALU ~20 -> ~10). Accuracy improves (RNE 0.4% vs q8 0.8%).

#define GCN_D 64

typedef float f4 __attribute__((ext_vector_type(4)));
typedef unsigned int u2 __attribute__((ext_vector_type(2)));
typedef unsigned int uv4 __attribute__((ext_vector_type(4)));

__device__ __forceinline__ unsigned bf16rne_pack(float lo, float hi) {
    // RNE f32->bf16, packed (lo in low half, hi in high half).
    unsigned ul = __float_as_uint(lo);
    unsigned uh = __float_as_uint(hi);
    ul = (ul + 0x7fffu + ((ul >> 16) & 1u)) >> 16;
    uh = (uh + 0x7fffu + ((uh >> 16) & 1u)) & 0xffff0000u;
    return ul | uh;
}

__global__ __launch_bounds__(256) void prep_kernel(
    const float* __restrict__ embeds,
    unsigned char* __restrict__ ebb,    // N x 64 bf16 (128 B/row)
    int quant_blocks,
    const int* __restrict__ edge_row, int* __restrict__ row_ptr, int E, int N)
{
    if ((int)blockIdx.x < quant_blocks) {
        // 8 lanes per row, 8 dims (32 B in, 16 B out) per lane.
        const int t   = blockIdx.x * blockDim.x + threadIdx.x;
        const int row = t >> 3;
        if (row >= N) return;
        const int l8 = (threadIdx.x & 7) * 8;

        const f4 a = __builtin_nontemporal_load(
            (const f4*)(embeds + (size_t)row * GCN_D + l8));
        const f4 b = __builtin_nontemporal_load(
            (const f4*)(embeds + (size_t)row * GCN_D + l8 + 4));

        uv4 p;
        p.x = bf16rne_pack(a.x, a.y);
        p.y = bf16rne_pack(a.z, a.w);
        p.z = bf16rne_pack(b.x, b.y);
        p.w = bf16rne_pack(b.z, b.w);

        *(uv4*)(ebb + (size_t)row * (GCN_D * 2) + l8 * 2) = p;
    } else {
        const int e = (blockIdx.x - quant_blocks) * blockDim.x + threadIdx.x;
        if (e >= E) return;
        const int r    = edge_row[e];
        const int prev = (e == 0) ? -1 : edge_row[e - 1];
        for (int k = prev + 1; k <= r; ++k) row_ptr[k] = e;
        if (e == E - 1)
            for (int k = r + 1; k <= N; ++k) row_ptr[k] = E;
    }
}

__global__ __launch_bounds__(256) void gcn_row_bf16_kernel(
    const int* __restrict__ row_ptr,
    const int* __restrict__ edge_col,
    const float* __restrict__ edge_val,
    const unsigned char* __restrict__ ebb,
    float* __restrict__ out,
    int N)
{
    const int tid = blockIdx.x * blockDim.x + threadIdx.x;
    const int row = tid >> 4;
    if (row >= N) return;
    const int off = (threadIdx.x & 15) * 8;   // byte offset into 128 B table row
    const int db  = (threadIdx.x & 15) * 4;   // float offset into out row

    const int p0 = row_ptr[row];
    const int p1 = row_ptr[row + 1];

    f4 acc = (f4)0.0f;

    if (p1 > p0) {
        const int nb = (p1 - p0 + 7) >> 3;    // padded 8-edge batches
        int k = p0;

        float wA[8], wB[8];
        u2    gA[8], gB[8];

        auto LOAD = [&](int kk, float* w, u2* g) {
            int c[8];
            #pragma unroll
            for (int j = 0; j < 8; ++j) {
                const int idx = (kk + j < p1) ? (kk + j) : (p1 - 1);
                c[j] = edge_col[idx];
                w[j] = (kk + j < p1) ? edge_val[idx] : 0.0f;
            }
            #pragma unroll
            for (int j = 0; j < 8; ++j)
                g[j] = *(const u2*)(ebb + (size_t)c[j] * (GCN_D * 2) + off);
        };
        auto COMP = [&](const float* w, const u2* g) {
            #pragma unroll
            for (int j = 0; j < 8; ++j) {
                const float x0 = __uint_as_float(g[j].x << 16);
                const float x1 = __uint_as_float(g[j].x & 0xffff0000u);
                const float x2 = __uint_as_float(g[j].y << 16);
                const float x3 = __uint_as_float(g[j].y & 0xffff0000u);
                acc.x = fmaf(w[j], x0, acc.x);
                acc.y = fmaf(w[j], x1, acc.y);
                acc.z = fmaf(w[j], x2, acc.z);
                acc.w = fmaf(w[j], x3, acc.w);
            }
        };

        // ping-pong pipeline: next batch's loads fly during this compute
        LOAD(k, wA, gA); k += 8;
        int b = 1;
        for (; b + 1 < nb; b += 2) {
            LOAD(k, wB, gB); k += 8;
            COMP(wA, gA);
            LOAD(k, wA, gA); k += 8;
            COMP(wB, gB);
        }
        if (b < nb) {
            LOAD(k, wB, gB);
            COMP(wA, gA);
            COMP(wB, gB);
        } else {
            COMP(wA, gA);
        }
    }

    __builtin_nontemporal_store(acc, (f4*)(out + (size_t)row * GCN_D + db));
}

extern "C" void kernel_launch(void* const* d_in, const int* in_sizes, int n_in,
                              void* d_out, int out_size, void* d_ws, size_t ws_size,
                              hipStream_t stream) {
    const int*   edge_row = (const int*)d_in[0];
    const int*   edge_col = (const int*)d_in[1];
    const float* edge_val = (const float*)d_in[2];
    const float* embeds   = (const float*)d_in[3];
    float*       out      = (float*)d_out;

    const int E = in_sizes[0];
    const int N = out_size / GCN_D;

    // ws layout: row_ptr | bf16 table (256B-aligned sections)
    int* row_ptr = (int*)d_ws;
    const size_t tb_off = (((size_t)(N + 1) * 4) + 255) & ~(size_t)255;
    unsigned char* ebb = (unsigned char*)d_ws + tb_off;

    const int quant_blocks = (N * 8 + 255) / 256;   // 8 lanes per row
    const int rp_blocks    = (E + 255) / 256;
    prep_kernel<<<quant_blocks + rp_blocks, 256, 0, stream>>>(
        embeds, ebb, quant_blocks, edge_row, row_ptr, E, N);

    const int row_blocks = (N * 16 + 255) / 256;    // 16 lanes per row
    gcn_row_bf16_kernel<<<row_blocks, 256, 0, stream>>>(
        row_ptr, edge_col, edge_val, ebb, out, N);
}